// Round 9
// baseline (237.796 us; speedup 1.0000x reference)
//
#include <hip/hip_runtime.h>

#define N_NODES 50000
#define N_EDGES 800000
#define IN_CH 128
#define OUT_CH 64
#define HEADS 4
#define HC 256  // HEADS*OUT_CH
#define NEG_SLOPE 0.2f
#define GEMM_BLOCKS 782    // ceil(50000/64)
#define COUNT_BLOCKS 782   // ceil(800000/1024)
#define SCAN_BLOCKS 49     // ceil(50000/1024)

// ---------------- workspace layout (bytes) ----------------
#define HB_OFF       0UL          // f16 h: 25,600,000
#define WSW_OFF      25600000UL   // swizzled f16 W: 65,536
#define ASRC_OFF     25665536UL   // 800,000
#define ADST_OFF     26465536UL   // 800,000
#define COUNTS_OFF   27265536UL   // 200,000
#define OFFSETS_OFF  27465536UL   // 200,000
#define BSUMS_OFF    27665536UL   // 1,024
#define RANK_OFF     27666560UL   // 4B/edge: 3,200,000
#define REC_OFF      30866560UL   // 16B/edge: 12,800,000 (16B aligned)
// total ≈ 43.7 MB

typedef __attribute__((ext_vector_type(8))) __fp16 f16x8;
typedef __attribute__((ext_vector_type(4))) unsigned uint32x4;
typedef __attribute__((ext_vector_type(4))) float f32x4;
typedef __attribute__((ext_vector_type(2))) __fp16 fp16x2;

__device__ __forceinline__ unsigned f2h2(float a, float b) {
  fp16x2 h = __builtin_amdgcn_cvt_pkrtz(a, b);  // v_cvt_pkrtz_f16_f32
  return __builtin_bit_cast(unsigned, h);
}
// fma_mix accumulate: acc += (float)f16 * e  ->  v_fma_mix_f32 (no cvt instrs)
__device__ __forceinline__ void fma2(float& a0, float& a1, unsigned u, float e) {
  fp16x2 h = __builtin_bit_cast(fp16x2, u);
  a0 = fmaf((float)h.x, e, a0);
  a1 = fmaf((float)h.y, e, a1);
}
__device__ __forceinline__ float lrelu(float e) {
  return e > 0.f ? e : NEG_SLOPE * e;
}
// extract head hd's f16 exp from a packed record {s, ex01, ex23, 0}
__device__ __forceinline__ float exhalf(uint32x4 r, int hd) {
  unsigned pair = (hd & 2) ? r.z : r.y;
  fp16x2 h = __builtin_bit_cast(fp16x2, pair);
  return (hd & 1) ? (float)h.y : (float)h.x;
}

// ---------------- init: W swizzle (blocks 0-15) + counts zero (blocks 16+) ----------------
__global__ __launch_bounds__(256) void init_k(const float* __restrict__ W,
                                              unsigned short* __restrict__ Wsw,
                                              int* __restrict__ counts) {
  if (blockIdx.x < 16) {
    int idx = blockIdx.x * 256 + threadIdx.x;  // 0..4095
    int l = idx & 63;
    int kc = (idx >> 6) & 3;
    int t = idx >> 8;
    int kbase = kc * 32 + (l >> 4) * 8;
    int col = t * 16 + (l & 15);
    unsigned int p[4];
#pragma unroll
    for (int j = 0; j < 4; ++j) {
      p[j] = f2h2(W[(size_t)(kbase + 2 * j) * HC + col],
                  W[(size_t)(kbase + 2 * j + 1) * HC + col]);
    }
    *(uint4*)(Wsw + (size_t)idx * 8) = make_uint4(p[0], p[1], p[2], p[3]);
  } else {
    int i = (blockIdx.x - 16) * 256 + threadIdx.x;
    if (i < N_NODES) counts[i] = 0;
  }
}

// ---------------- MFMA GEMM (f16, swapped operands, LDS-free) + fused logits ----------------
// mfma(W_frag, x_frag) -> D[channel][xrow]: lane l holds channels t*16+(l>>4)*4+{0..3}
// of x-row (l&15). f16 pack is in-register; no LDS, no syncthreads.
__global__ __launch_bounds__(256) void gemm_count(const float* __restrict__ x,
                                                  const unsigned short* __restrict__ Wsw,
                                                  const float* __restrict__ att_s,
                                                  const float* __restrict__ att_d,
                                                  const int* __restrict__ dstv,
                                                  unsigned short* __restrict__ hb,
                                                  float* __restrict__ a_src,
                                                  float* __restrict__ a_dst,
                                                  int* __restrict__ counts,
                                                  int* __restrict__ rank) {
  if (blockIdx.x >= GEMM_BLOCKS) {  // ---- count role: one atomic pass, rank recorded ----
    int base = (blockIdx.x - GEMM_BLOCKS) * 1024 + threadIdx.x;
#pragma unroll
    for (int k = 0; k < 4; ++k) {
      int e = base + k * 256;
      if (e < N_EDGES) {
        int d = __builtin_nontemporal_load(&dstv[e]);
        int r = atomicAdd(&counts[d], 1);
        __builtin_nontemporal_store(r, &rank[e]);
      }
    }
    return;
  }

  const int wave = threadIdx.x >> 6;
  const int l = threadIdx.x & 63;
  const int q = l >> 4;
  const int m = l & 15;
  const int mrow = blockIdx.x * 64 + wave * 16 + m;
  const bool mvalid = mrow < N_NODES;
  const int rc = mvalid ? mrow : (N_NODES - 1);

  // x fragment (B-operand): lane provides x[row=l&15][k=(l>>4)*8 + kc*32 + j]
  f16x8 a[4];
  const float* xr = x + (size_t)rc * IN_CH + q * 8;
#pragma unroll
  for (int kc = 0; kc < 4; ++kc) {
    float4 u = *(const float4*)(xr + kc * 32);
    float4 v = *(const float4*)(xr + kc * 32 + 4);
    uint32x4 t;
    t[0] = f2h2(u.x, u.y);
    t[1] = f2h2(u.z, u.w);
    t[2] = f2h2(v.x, v.y);
    t[3] = f2h2(v.z, v.w);
    a[kc] = __builtin_bit_cast(f16x8, t);
  }

  float as[4] = {0.f, 0.f, 0.f, 0.f};
  float ad[4] = {0.f, 0.f, 0.f, 0.f};
  unsigned short* hrow = hb + (size_t)mrow * HC;

#pragma unroll
  for (int t = 0; t < 16; ++t) {
    f32x4 acc = {0.f, 0.f, 0.f, 0.f};
#pragma unroll
    for (int kc = 0; kc < 4; ++kc) {
      f16x8 w = *(const f16x8*)(Wsw + ((size_t)(t * 4 + kc) * 64 + l) * 8);
      acc = __builtin_amdgcn_mfma_f32_16x16x32_f16(w, a[kc], acc, 0, 0, 0);
    }
    const int ch = t * 16 + q * 4;      // 4 consecutive channels in this lane
    const int hh = t >> 2;              // head = ch/64 (static under unroll)
    float4 sv = *(const float4*)(att_s + ch);
    float4 dv = *(const float4*)(att_d + ch);
    as[hh] += acc[0] * sv.x + acc[1] * sv.y + acc[2] * sv.z + acc[3] * sv.w;
    ad[hh] += acc[0] * dv.x + acc[1] * dv.y + acc[2] * dv.z + acc[3] * dv.w;
    if (mvalid) {
      uint2 p;
      p.x = f2h2(acc[0], acc[1]);
      p.y = f2h2(acc[2], acc[3]);
      *(uint2*)(hrow + ch) = p;  // 8B aligned (ch multiple of 4)
    }
  }

  // reduce logits across the 4 q-groups (channel slices)
#pragma unroll
  for (int h = 0; h < 4; ++h) {
    as[h] += __shfl_xor(as[h], 16);
    as[h] += __shfl_xor(as[h], 32);
    ad[h] += __shfl_xor(ad[h], 16);
    ad[h] += __shfl_xor(ad[h], 32);
  }
  if (l < 16 && mvalid) {
    *(float4*)(a_src + (size_t)mrow * 4) = make_float4(as[0], as[1], as[2], as[3]);
    *(float4*)(a_dst + (size_t)mrow * 4) = make_float4(ad[0], ad[1], ad[2], ad[3]);
  }
}

// ---------------- scan ----------------
__global__ __launch_bounds__(256) void scan1(const int* __restrict__ counts,
                                             int* __restrict__ offsets,
                                             int* __restrict__ bsums) {
  __shared__ int sd[256];
  const int base = blockIdx.x * 1024;
  const int t = threadIdx.x;
  int v[4];
  int tsum = 0;
#pragma unroll
  for (int k = 0; k < 4; ++k) {
    int i = base + t * 4 + k;
    v[k] = (i < N_NODES) ? counts[i] : 0;
    tsum += v[k];
  }
  sd[t] = tsum;
  __syncthreads();
  for (int off = 1; off < 256; off <<= 1) {
    int xval = (t >= off) ? sd[t - off] : 0;
    __syncthreads();
    sd[t] += xval;
    __syncthreads();
  }
  int excl = sd[t] - tsum;
  int run = excl;
#pragma unroll
  for (int k = 0; k < 4; ++k) {
    int i = base + t * 4 + k;
    if (i < N_NODES) offsets[i] = run;
    run += v[k];
  }
  if (t == 255) bsums[blockIdx.x] = sd[255];
}

// scan2+scan3 fused: every block redundantly wave-scans the 49 block sums.
__global__ __launch_bounds__(256) void scan23(int* __restrict__ offsets,
                                              const int* __restrict__ bsums) {
  __shared__ int s_add;
  if (threadIdx.x < 64) {
    int lane = threadIdx.x;
    int v = (lane < SCAN_BLOCKS) ? bsums[lane] : 0;
#pragma unroll
    for (int o = 1; o < 64; o <<= 1) {
      int t = __shfl_up(v, o);
      if (lane >= o) v += t;
    }
    int b = blockIdx.x;
    int pre = (b == 0) ? 0 : __shfl(v, b - 1);
    if (lane == 0) s_add = pre;
  }
  __syncthreads();
  const int add = s_add;
  const int base = blockIdx.x * 1024;
  const int t = threadIdx.x;
#pragma unroll
  for (int k = 0; k < 4; ++k) {
    int i = base + t * 4 + k;
    if (i < N_NODES) offsets[i] += add;
  }
}

// ---------------- scatter: atomic-free, one 16B record {s, ex01, ex23, 0} per edge ----------------
// rec stores are non-temporal: avoids write-allocate of scattered partial lines.
__global__ __launch_bounds__(256) void scatter_k(const int* __restrict__ src,
                                                 const int* __restrict__ dst,
                                                 const int* __restrict__ rank,
                                                 const int* __restrict__ offsets,
                                                 const float* __restrict__ a_src,
                                                 const float* __restrict__ a_dst,
                                                 uint32x4* __restrict__ rec) {
  int e = blockIdx.x * 256 + threadIdx.x;
  if (e < N_EDGES) {
    int s = __builtin_nontemporal_load(&src[e]);
    int d = __builtin_nontemporal_load(&dst[e]);
    int r = __builtin_nontemporal_load(&rank[e]);
    float4 as = *(const float4*)(a_src + s * 4);
    float4 ad = *(const float4*)(a_dst + d * 4);
    float ex0 = __expf(lrelu(as.x + ad.x));
    float ex1 = __expf(lrelu(as.y + ad.y));
    float ex2 = __expf(lrelu(as.z + ad.z));
    float ex3 = __expf(lrelu(as.w + ad.w));
    int pos = offsets[d] + r;
    uint32x4 rv = {(unsigned)s, f2h2(ex0, ex1), f2h2(ex2, ex3), 0u};
    __builtin_nontemporal_store(rv, &rec[pos]);
  }
}

// ---------------- aggregate: 4 edge groups x 16 lanes, 2 edges in flight per group ----------------
// rec loads and out stores are non-temporal: keep L2 for the h working set.
__global__ __launch_bounds__(256) void aggregate(const unsigned short* __restrict__ hb,
                                                 const float* __restrict__ a_src,
                                                 const float* __restrict__ a_dst,
                                                 const int* __restrict__ counts,
                                                 const int* __restrict__ offsets,
                                                 const uint32x4* __restrict__ rec,
                                                 const float* __restrict__ bias,
                                                 float* __restrict__ out) {
  const int node = blockIdx.x * 4 + (threadIdx.x >> 6);
  const int l = threadIdx.x & 63;
  const int g = l >> 4;   // edge-parity group 0..3
  const int q = l & 15;   // channel slice: 16 channels at c0=q*16
  const int hd = q >> 2;
  const int cb = q * 32;  // byte offset into 512B row
  const int deg = counts[node];
  const int start = offsets[node];
  const char* hbase = (const char*)hb;

  float denom = 0.f;
  float acc[16];
#pragma unroll
  for (int k = 0; k < 16; ++k) acc[k] = 0.f;

  // group g covers edge indices {j+g, j+g+4} for j = 0,8,16,...
  for (int j = 0; j + g < deg; j += 8) {
    int i0 = start + j + g;
    bool v1 = (j + g + 4) < deg;
    int i1 = v1 ? (i0 + 4) : i0;
    // two broadcast 16B record loads (non-temporal: read-once stream)
    uint32x4 r0 = __builtin_nontemporal_load(&rec[i0]);
    uint32x4 r1 = __builtin_nontemporal_load(&rec[i1]);
    int s0 = (int)r0.x;
    int s1 = (int)r1.x;
    float ex0 = exhalf(r0, hd);
    float ex1 = v1 ? exhalf(r1, hd) : 0.f;
    // two independent 32B h gathers (cached: the reused working set)
    const char* hp0 = hbase + (size_t)s0 * 512 + cb;
    const char* hp1 = hbase + (size_t)s1 * 512 + cb;
    uint4 A0 = *(const uint4*)hp0;
    uint4 A1 = *(const uint4*)(hp0 + 16);
    uint4 B0 = *(const uint4*)hp1;
    uint4 B1 = *(const uint4*)(hp1 + 16);
    denom += ex0 + ex1;
    fma2(acc[0],  acc[1],  A0.x, ex0);  fma2(acc[2],  acc[3],  A0.y, ex0);
    fma2(acc[4],  acc[5],  A0.z, ex0);  fma2(acc[6],  acc[7],  A0.w, ex0);
    fma2(acc[8],  acc[9],  A1.x, ex0);  fma2(acc[10], acc[11], A1.y, ex0);
    fma2(acc[12], acc[13], A1.z, ex0);  fma2(acc[14], acc[15], A1.w, ex0);
    fma2(acc[0],  acc[1],  B0.x, ex1);  fma2(acc[2],  acc[3],  B0.y, ex1);
    fma2(acc[4],  acc[5],  B0.z, ex1);  fma2(acc[6],  acc[7],  B0.w, ex1);
    fma2(acc[8],  acc[9],  B1.x, ex1);  fma2(acc[10], acc[11], B1.y, ex1);
    fma2(acc[12], acc[13], B1.z, ex1);  fma2(acc[14], acc[15], B1.w, ex1);
  }

  // combine the 4 edge groups
  denom += __shfl_xor(denom, 16);
  denom += __shfl_xor(denom, 32);
#pragma unroll
  for (int k = 0; k < 16; ++k) {
    acc[k] += __shfl_xor(acc[k], 16);
    acc[k] += __shfl_xor(acc[k], 32);
  }

  // self-loop (identical across groups; added once per lane)
  float es = a_src[node * HEADS + hd] + a_dst[node * HEADS + hd];
  float exs = __expf(lrelu(es));
  denom += exs;
  const char* hp = hbase + (size_t)node * 512 + cb;
  uint4 h0 = *(const uint4*)hp;
  uint4 h1 = *(const uint4*)(hp + 16);
  fma2(acc[0],  acc[1],  h0.x, exs);  fma2(acc[2],  acc[3],  h0.y, exs);
  fma2(acc[4],  acc[5],  h0.z, exs);  fma2(acc[6],  acc[7],  h0.w, exs);
  fma2(acc[8],  acc[9],  h1.x, exs);  fma2(acc[10], acc[11], h1.y, exs);
  fma2(acc[12], acc[13], h1.z, exs);  fma2(acc[14], acc[15], h1.w, exs);

  float inv = 1.f / (denom + 1e-16f);
  // each group stores its own float4 slice: channels q*16 + g*4 .. +3
  int c = q * 16 + g * 4;
  float4 bv = *(const float4*)(bias + c);
  f32x4 o = {acc[g * 4 + 0] * inv + bv.x, acc[g * 4 + 1] * inv + bv.y,
             acc[g * 4 + 2] * inv + bv.z, acc[g * 4 + 3] * inv + bv.w};
  __builtin_nontemporal_store(o, (f32x4*)(out + (size_t)node * HC + c));
}

extern "C" void kernel_launch(void* const* d_in, const int* in_sizes, int n_in,
                              void* d_out, int out_size, void* d_ws, size_t ws_size,
                              hipStream_t stream) {
  const float* x     = (const float*)d_in[0];
  const int*   ei    = (const int*)d_in[1];
  const float* W     = (const float*)d_in[2];
  const float* att_s = (const float*)d_in[3];
  const float* att_d = (const float*)d_in[4];
  const float* bias  = (const float*)d_in[5];
  float* out = (float*)d_out;

  char* ws = (char*)d_ws;
  unsigned short* hb  = (unsigned short*)(ws + HB_OFF);
  unsigned short* Wsw = (unsigned short*)(ws + WSW_OFF);
  float* a_src  = (float*)(ws + ASRC_OFF);
  float* a_dst  = (float*)(ws + ADST_OFF);
  int* counts   = (int*)(ws + COUNTS_OFF);
  int* offsets  = (int*)(ws + OFFSETS_OFF);
  int* bsums    = (int*)(ws + BSUMS_OFF);
  int* rank     = (int*)(ws + RANK_OFF);
  uint32x4* rec = (uint32x4*)(ws + REC_OFF);

  const int* src = ei;             // edge_index[0]
  const int* dst = ei + N_EDGES;   // edge_index[1]

  init_k<<<16 + 196, 256, 0, stream>>>(W, Wsw, counts);
  gemm_count<<<GEMM_BLOCKS + COUNT_BLOCKS, 256, 0, stream>>>(
      x, Wsw, att_s, att_d, dst, hb, a_src, a_dst, counts, rank);
  scan1<<<SCAN_BLOCKS, 256, 0, stream>>>(counts, offsets, bsums);
  scan23<<<SCAN_BLOCKS, 256, 0, stream>>>(offsets, bsums);
  scatter_k<<<3125, 256, 0, stream>>>(src, dst, rank, offsets, a_src, a_dst, rec);
  aggregate<<<12500, 256, 0, stream>>>(hb, a_src, a_dst, counts, offsets, rec, bias, out);
}

// Round 10
// 223.636 us; speedup vs baseline: 1.0633x; 1.0633x over previous
//
#include <hip/hip_runtime.h>

#define N_NODES 50000
#define N_EDGES 800000
#define IN_CH 128
#define OUT_CH 64
#define HEADS 4
#define HC 256  // HEADS*OUT_CH
#define NEG_SLOPE 0.2f
#define GEMM_BLOCKS 782    // ceil(50000/64)
#define COUNT_BLOCKS 1563  // ceil(800000/512)
#define SCAN_BLOCKS 49     // ceil(50000/1024)
#define CSTRIDE 32         // 1 counter per 128B line (atomic de-conflict)

// ---------------- workspace layout (bytes) ----------------
#define HB_OFF       0UL          // f16 h: 25,600,000
#define WSW_OFF      25600000UL   // swizzled f16 W: 65,536
#define ASRC_OFF     25665536UL   // 800,000
#define ADST_OFF     26465536UL   // 800,000
#define COUNTS_OFF   27265536UL   // padded: 50000*128 = 6,400,000
#define OFFSETS_OFF  33665536UL   // 200,000
#define BSUMS_OFF    33865536UL   // 1,024
#define RANK_OFF     33866560UL   // 4B/edge: 3,200,000
#define REC_OFF      37066560UL   // 16B/edge: 12,800,000 (16B aligned)
// total ≈ 49.9 MB

typedef __attribute__((ext_vector_type(8))) __fp16 f16x8;
typedef __attribute__((ext_vector_type(4))) unsigned uint32x4;
typedef __attribute__((ext_vector_type(4))) float f32x4;
typedef __attribute__((ext_vector_type(2))) __fp16 fp16x2;

__device__ __forceinline__ unsigned f2h2(float a, float b) {
  fp16x2 h = __builtin_amdgcn_cvt_pkrtz(a, b);  // v_cvt_pkrtz_f16_f32
  return __builtin_bit_cast(unsigned, h);
}
// fma_mix accumulate: acc += (float)f16 * e  ->  v_fma_mix_f32 (no cvt instrs)
__device__ __forceinline__ void fma2(float& a0, float& a1, unsigned u, float e) {
  fp16x2 h = __builtin_bit_cast(fp16x2, u);
  a0 = fmaf((float)h.x, e, a0);
  a1 = fmaf((float)h.y, e, a1);
}
__device__ __forceinline__ float lrelu(float e) {
  return e > 0.f ? e : NEG_SLOPE * e;
}
// extract head hd's f16 exp from a packed record {s, ex01, ex23, 0}
__device__ __forceinline__ float exhalf(uint4 r, int hd) {
  unsigned pair = (hd & 2) ? r.z : r.y;
  fp16x2 h = __builtin_bit_cast(fp16x2, pair);
  return (hd & 1) ? (float)h.y : (float)h.x;
}

// ---------------- init: W swizzle only (counts zeroed by hipMemsetAsync) ----------------
__global__ __launch_bounds__(256) void init_k(const float* __restrict__ W,
                                              unsigned short* __restrict__ Wsw) {
  int idx = blockIdx.x * 256 + threadIdx.x;  // 0..4095
  int l = idx & 63;
  int kc = (idx >> 6) & 3;
  int t = idx >> 8;
  int kbase = kc * 32 + (l >> 4) * 8;
  int col = t * 16 + (l & 15);
  unsigned int p[4];
#pragma unroll
  for (int j = 0; j < 4; ++j) {
    p[j] = f2h2(W[(size_t)(kbase + 2 * j) * HC + col],
                W[(size_t)(kbase + 2 * j + 1) * HC + col]);
  }
  *(uint4*)(Wsw + (size_t)idx * 8) = make_uint4(p[0], p[1], p[2], p[3]);
}

// ---------------- MFMA GEMM (f16, swapped operands, LDS-free) + fused logits ----------------
// mfma(W_frag, x_frag) -> D[channel][xrow]: lane l holds channels t*16+(l>>4)*4+{0..3}
// of x-row (l&15). f16 pack is in-register; no LDS, no syncthreads.
// Count role: padded counters (1/128B line) kill cross-XCD line conflicts.
__global__ __launch_bounds__(256) void gemm_count(const float* __restrict__ x,
                                                  const unsigned short* __restrict__ Wsw,
                                                  const float* __restrict__ att_s,
                                                  const float* __restrict__ att_d,
                                                  const int* __restrict__ dstv,
                                                  unsigned short* __restrict__ hb,
                                                  float* __restrict__ a_src,
                                                  float* __restrict__ a_dst,
                                                  int* __restrict__ counts,
                                                  int* __restrict__ rank) {
  if (blockIdx.x >= GEMM_BLOCKS) {  // ---- count role: one atomic pass, rank recorded ----
    int base = (blockIdx.x - GEMM_BLOCKS) * 512 + threadIdx.x;
#pragma unroll
    for (int k = 0; k < 2; ++k) {
      int e = base + k * 256;
      if (e < N_EDGES) rank[e] = atomicAdd(&counts[(size_t)dstv[e] * CSTRIDE], 1);
    }
    return;
  }

  const int wave = threadIdx.x >> 6;
  const int l = threadIdx.x & 63;
  const int q = l >> 4;
  const int m = l & 15;
  const int mrow = blockIdx.x * 64 + wave * 16 + m;
  const bool mvalid = mrow < N_NODES;
  const int rc = mvalid ? mrow : (N_NODES - 1);

  // x fragment (B-operand): lane provides x[row=l&15][k=(l>>4)*8 + kc*32 + j]
  f16x8 a[4];
  const float* xr = x + (size_t)rc * IN_CH + q * 8;
#pragma unroll
  for (int kc = 0; kc < 4; ++kc) {
    float4 u = *(const float4*)(xr + kc * 32);
    float4 v = *(const float4*)(xr + kc * 32 + 4);
    uint32x4 t;
    t[0] = f2h2(u.x, u.y);
    t[1] = f2h2(u.z, u.w);
    t[2] = f2h2(v.x, v.y);
    t[3] = f2h2(v.z, v.w);
    a[kc] = __builtin_bit_cast(f16x8, t);
  }

  float as[4] = {0.f, 0.f, 0.f, 0.f};
  float ad[4] = {0.f, 0.f, 0.f, 0.f};
  unsigned short* hrow = hb + (size_t)mrow * HC;

#pragma unroll
  for (int t = 0; t < 16; ++t) {
    f32x4 acc = {0.f, 0.f, 0.f, 0.f};
#pragma unroll
    for (int kc = 0; kc < 4; ++kc) {
      f16x8 w = *(const f16x8*)(Wsw + ((size_t)(t * 4 + kc) * 64 + l) * 8);
      acc = __builtin_amdgcn_mfma_f32_16x16x32_f16(w, a[kc], acc, 0, 0, 0);
    }
    const int ch = t * 16 + q * 4;      // 4 consecutive channels in this lane
    const int hh = t >> 2;              // head = ch/64 (static under unroll)
    float4 sv = *(const float4*)(att_s + ch);
    float4 dv = *(const float4*)(att_d + ch);
    as[hh] += acc[0] * sv.x + acc[1] * sv.y + acc[2] * sv.z + acc[3] * sv.w;
    ad[hh] += acc[0] * dv.x + acc[1] * dv.y + acc[2] * dv.z + acc[3] * dv.w;
    if (mvalid) {
      uint2 p;
      p.x = f2h2(acc[0], acc[1]);
      p.y = f2h2(acc[2], acc[3]);
      *(uint2*)(hrow + ch) = p;  // 8B aligned (ch multiple of 4)
    }
  }

  // reduce logits across the 4 q-groups (channel slices)
#pragma unroll
  for (int h = 0; h < 4; ++h) {
    as[h] += __shfl_xor(as[h], 16);
    as[h] += __shfl_xor(as[h], 32);
    ad[h] += __shfl_xor(ad[h], 16);
    ad[h] += __shfl_xor(ad[h], 32);
  }
  if (l < 16 && mvalid) {
    *(float4*)(a_src + (size_t)mrow * 4) = make_float4(as[0], as[1], as[2], as[3]);
    *(float4*)(a_dst + (size_t)mrow * 4) = make_float4(ad[0], ad[1], ad[2], ad[3]);
  }
}

// ---------------- scan ----------------
__global__ __launch_bounds__(256) void scan1(const int* __restrict__ counts,
                                             int* __restrict__ offsets,
                                             int* __restrict__ bsums) {
  __shared__ int sd[256];
  const int base = blockIdx.x * 1024;
  const int t = threadIdx.x;
  int v[4];
  int tsum = 0;
#pragma unroll
  for (int k = 0; k < 4; ++k) {
    int i = base + t * 4 + k;
    v[k] = (i < N_NODES) ? counts[(size_t)i * CSTRIDE] : 0;
    tsum += v[k];
  }
  sd[t] = tsum;
  __syncthreads();
  for (int off = 1; off < 256; off <<= 1) {
    int xval = (t >= off) ? sd[t - off] : 0;
    __syncthreads();
    sd[t] += xval;
    __syncthreads();
  }
  int excl = sd[t] - tsum;
  int run = excl;
#pragma unroll
  for (int k = 0; k < 4; ++k) {
    int i = base + t * 4 + k;
    if (i < N_NODES) offsets[i] = run;
    run += v[k];
  }
  if (t == 255) bsums[blockIdx.x] = sd[255];
}

// scan2+scan3 fused: every block redundantly wave-scans the 49 block sums.
__global__ __launch_bounds__(256) void scan23(int* __restrict__ offsets,
                                              const int* __restrict__ bsums) {
  __shared__ int s_add;
  if (threadIdx.x < 64) {
    int lane = threadIdx.x;
    int v = (lane < SCAN_BLOCKS) ? bsums[lane] : 0;
#pragma unroll
    for (int o = 1; o < 64; o <<= 1) {
      int t = __shfl_up(v, o);
      if (lane >= o) v += t;
    }
    int b = blockIdx.x;
    int pre = (b == 0) ? 0 : __shfl(v, b - 1);
    if (lane == 0) s_add = pre;
  }
  __syncthreads();
  const int add = s_add;
  const int base = blockIdx.x * 1024;
  const int t = threadIdx.x;
#pragma unroll
  for (int k = 0; k < 4; ++k) {
    int i = base + t * 4 + k;
    if (i < N_NODES) offsets[i] += add;
  }
}

// ---------------- scatter: atomic-free, one 16B record {s, ex01, ex23, 0} per edge ----------------
__global__ __launch_bounds__(256) void scatter_k(const int* __restrict__ src,
                                                 const int* __restrict__ dst,
                                                 const int* __restrict__ rank,
                                                 const int* __restrict__ offsets,
                                                 const float* __restrict__ a_src,
                                                 const float* __restrict__ a_dst,
                                                 uint4* __restrict__ rec) {
  int e = blockIdx.x * 256 + threadIdx.x;
  if (e < N_EDGES) {
    int s = src[e];
    int d = dst[e];
    float4 as = *(const float4*)(a_src + s * 4);
    float4 ad = *(const float4*)(a_dst + d * 4);
    float ex0 = __expf(lrelu(as.x + ad.x));
    float ex1 = __expf(lrelu(as.y + ad.y));
    float ex2 = __expf(lrelu(as.z + ad.z));
    float ex3 = __expf(lrelu(as.w + ad.w));
    int pos = offsets[d] + rank[e];
    rec[pos] = make_uint4((unsigned)s, f2h2(ex0, ex1), f2h2(ex2, ex3), 0u);
  }
}

// ---------------- aggregate: 4 edge groups x 16 lanes, 2 edges in flight per group ----------------
__global__ __launch_bounds__(256) void aggregate(const unsigned short* __restrict__ hb,
                                                 const float* __restrict__ a_src,
                                                 const float* __restrict__ a_dst,
                                                 const int* __restrict__ counts,
                                                 const int* __restrict__ offsets,
                                                 const uint4* __restrict__ rec,
                                                 const float* __restrict__ bias,
                                                 float* __restrict__ out) {
  const int node = blockIdx.x * 4 + (threadIdx.x >> 6);
  const int l = threadIdx.x & 63;
  const int g = l >> 4;   // edge-parity group 0..3
  const int q = l & 15;   // channel slice: 16 channels at c0=q*16
  const int hd = q >> 2;
  const int cb = q * 32;  // byte offset into 512B row
  const int deg = counts[(size_t)node * CSTRIDE];
  const int start = offsets[node];
  const char* hbase = (const char*)hb;

  float denom = 0.f;
  float acc[16];
#pragma unroll
  for (int k = 0; k < 16; ++k) acc[k] = 0.f;

  // group g covers edge indices {j+g, j+g+4} for j = 0,8,16,...
  for (int j = 0; j + g < deg; j += 8) {
    int i0 = start + j + g;
    bool v1 = (j + g + 4) < deg;
    int i1 = v1 ? (i0 + 4) : i0;
    // two broadcast 16B record loads
    uint4 r0 = rec[i0];
    uint4 r1 = rec[i1];
    int s0 = (int)r0.x;
    int s1 = (int)r1.x;
    float ex0 = exhalf(r0, hd);
    float ex1 = v1 ? exhalf(r1, hd) : 0.f;
    // two independent 32B h gathers
    const char* hp0 = hbase + (size_t)s0 * 512 + cb;
    const char* hp1 = hbase + (size_t)s1 * 512 + cb;
    uint4 A0 = *(const uint4*)hp0;
    uint4 A1 = *(const uint4*)(hp0 + 16);
    uint4 B0 = *(const uint4*)hp1;
    uint4 B1 = *(const uint4*)(hp1 + 16);
    denom += ex0 + ex1;
    fma2(acc[0],  acc[1],  A0.x, ex0);  fma2(acc[2],  acc[3],  A0.y, ex0);
    fma2(acc[4],  acc[5],  A0.z, ex0);  fma2(acc[6],  acc[7],  A0.w, ex0);
    fma2(acc[8],  acc[9],  A1.x, ex0);  fma2(acc[10], acc[11], A1.y, ex0);
    fma2(acc[12], acc[13], A1.z, ex0);  fma2(acc[14], acc[15], A1.w, ex0);
    fma2(acc[0],  acc[1],  B0.x, ex1);  fma2(acc[2],  acc[3],  B0.y, ex1);
    fma2(acc[4],  acc[5],  B0.z, ex1);  fma2(acc[6],  acc[7],  B0.w, ex1);
    fma2(acc[8],  acc[9],  B1.x, ex1);  fma2(acc[10], acc[11], B1.y, ex1);
    fma2(acc[12], acc[13], B1.z, ex1);  fma2(acc[14], acc[15], B1.w, ex1);
  }

  // combine the 4 edge groups
  denom += __shfl_xor(denom, 16);
  denom += __shfl_xor(denom, 32);
#pragma unroll
  for (int k = 0; k < 16; ++k) {
    acc[k] += __shfl_xor(acc[k], 16);
    acc[k] += __shfl_xor(acc[k], 32);
  }

  // self-loop (identical across groups; added once per lane)
  float es = a_src[node * HEADS + hd] + a_dst[node * HEADS + hd];
  float exs = __expf(lrelu(es));
  denom += exs;
  const char* hp = hbase + (size_t)node * 512 + cb;
  uint4 h0 = *(const uint4*)hp;
  uint4 h1 = *(const uint4*)(hp + 16);
  fma2(acc[0],  acc[1],  h0.x, exs);  fma2(acc[2],  acc[3],  h0.y, exs);
  fma2(acc[4],  acc[5],  h0.z, exs);  fma2(acc[6],  acc[7],  h0.w, exs);
  fma2(acc[8],  acc[9],  h1.x, exs);  fma2(acc[10], acc[11], h1.y, exs);
  fma2(acc[12], acc[13], h1.z, exs);  fma2(acc[14], acc[15], h1.w, exs);

  float inv = 1.f / (denom + 1e-16f);
  // each group stores its own float4 slice: channels q*16 + g*4 .. +3
  int c = q * 16 + g * 4;
  float4 bv = *(const float4*)(bias + c);
  float4 o = make_float4(acc[g * 4 + 0] * inv + bv.x, acc[g * 4 + 1] * inv + bv.y,
                         acc[g * 4 + 2] * inv + bv.z, acc[g * 4 + 3] * inv + bv.w);
  *(float4*)(out + (size_t)node * HC + c) = o;
}

extern "C" void kernel_launch(void* const* d_in, const int* in_sizes, int n_in,
                              void* d_out, int out_size, void* d_ws, size_t ws_size,
                              hipStream_t stream) {
  const float* x     = (const float*)d_in[0];
  const int*   ei    = (const int*)d_in[1];
  const float* W     = (const float*)d_in[2];
  const float* att_s = (const float*)d_in[3];
  const float* att_d = (const float*)d_in[4];
  const float* bias  = (const float*)d_in[5];
  float* out = (float*)d_out;

  char* ws = (char*)d_ws;
  unsigned short* hb  = (unsigned short*)(ws + HB_OFF);
  unsigned short* Wsw = (unsigned short*)(ws + WSW_OFF);
  float* a_src  = (float*)(ws + ASRC_OFF);
  float* a_dst  = (float*)(ws + ADST_OFF);
  int* counts   = (int*)(ws + COUNTS_OFF);
  int* offsets  = (int*)(ws + OFFSETS_OFF);
  int* bsums    = (int*)(ws + BSUMS_OFF);
  int* rank     = (int*)(ws + RANK_OFF);
  uint4* rec    = (uint4*)(ws + REC_OFF);

  const int* src = ei;             // edge_index[0]
  const int* dst = ei + N_EDGES;   // edge_index[1]

  hipMemsetAsync(counts, 0, (size_t)N_NODES * CSTRIDE * 4, stream);
  init_k<<<16, 256, 0, stream>>>(W, Wsw);
  gemm_count<<<GEMM_BLOCKS + COUNT_BLOCKS, 256, 0, stream>>>(
      x, Wsw, att_s, att_d, dst, hb, a_src, a_dst, counts, rank);
  scan1<<<SCAN_BLOCKS, 256, 0, stream>>>(counts, offsets, bsums);
  scan23<<<SCAN_BLOCKS, 256, 0, stream>>>(offsets, bsums);
  scatter_k<<<3125, 256, 0, stream>>>(src, dst, rank, offsets, a_src, a_dst, rec);
  aggregate<<<12500, 256, 0, stream>>>(hb, a_src, a_dst, counts, offsets, rec, bias, out);
}

// Round 11
// 221.578 us; speedup vs baseline: 1.0732x; 1.0093x over previous
//
#include <hip/hip_runtime.h>

#define N_NODES 50000
#define N_EDGES 800000
#define IN_CH 128
#define OUT_CH 64
#define HEADS 4
#define HC 256  // HEADS*OUT_CH
#define NEG_SLOPE 0.2f
#define GEMM_BLOCKS 782    // ceil(50000/64)
#define COUNT_BLOCKS 1563  // ceil(800000/512)
#define SCAN_BLOCKS 49     // ceil(50000/1024)

// ---------------- workspace layout (bytes) ----------------
#define HB_OFF       0UL          // f16 h: 25,600,000
#define WSW_OFF      25600000UL   // swizzled f16 W: 65,536
#define ASRC_OFF     25665536UL   // 800,000
#define ADST_OFF     26465536UL   // 800,000
#define COUNTS_OFF   27265536UL   // 200,000
#define OFFSETS_OFF  27465536UL   // 200,000 (partial per-scanblock offsets)
#define BSUMS_OFF    27665536UL   // 1,024
#define RANK_OFF     27666560UL   // 4B/edge: 3,200,000
#define REC_OFF      30866560UL   // 16B/edge: 12,800,000 (16B aligned)
// total ≈ 43.7 MB

typedef __attribute__((ext_vector_type(8))) __fp16 f16x8;
typedef __attribute__((ext_vector_type(4))) unsigned uint32x4;
typedef __attribute__((ext_vector_type(4))) float f32x4;
typedef __attribute__((ext_vector_type(2))) __fp16 fp16x2;

__device__ __forceinline__ unsigned f2h2(float a, float b) {
  fp16x2 h = __builtin_amdgcn_cvt_pkrtz(a, b);  // v_cvt_pkrtz_f16_f32
  return __builtin_bit_cast(unsigned, h);
}
// fma_mix accumulate: acc += (float)f16 * e  ->  v_fma_mix_f32 (no cvt instrs)
__device__ __forceinline__ void fma2(float& a0, float& a1, unsigned u, float e) {
  fp16x2 h = __builtin_bit_cast(fp16x2, u);
  a0 = fmaf((float)h.x, e, a0);
  a1 = fmaf((float)h.y, e, a1);
}
__device__ __forceinline__ float lrelu(float e) {
  return e > 0.f ? e : NEG_SLOPE * e;
}
// extract head hd's f16 exp from a packed record {s, ex01, ex23, 0}
__device__ __forceinline__ float exhalf(uint4 r, int hd) {
  unsigned pair = (hd & 2) ? r.z : r.y;
  fp16x2 h = __builtin_bit_cast(fp16x2, pair);
  return (hd & 1) ? (float)h.y : (float)h.x;
}

// ---------------- init: W swizzle (blocks 0-15) + counts zero (blocks 16+) ----------------
__global__ __launch_bounds__(256) void init_k(const float* __restrict__ W,
                                              unsigned short* __restrict__ Wsw,
                                              int* __restrict__ counts) {
  if (blockIdx.x < 16) {
    int idx = blockIdx.x * 256 + threadIdx.x;  // 0..4095
    int l = idx & 63;
    int kc = (idx >> 6) & 3;
    int t = idx >> 8;
    int kbase = kc * 32 + (l >> 4) * 8;
    int col = t * 16 + (l & 15);
    unsigned int p[4];
#pragma unroll
    for (int j = 0; j < 4; ++j) {
      p[j] = f2h2(W[(size_t)(kbase + 2 * j) * HC + col],
                  W[(size_t)(kbase + 2 * j + 1) * HC + col]);
    }
    *(uint4*)(Wsw + (size_t)idx * 8) = make_uint4(p[0], p[1], p[2], p[3]);
  } else {
    int i = (blockIdx.x - 16) * 256 + threadIdx.x;
    if (i < N_NODES) counts[i] = 0;
  }
}

// ---------------- MFMA GEMM (f16, swapped operands, LDS-free) + fused logits ----------------
// mfma(W_frag, x_frag) -> D[channel][xrow]: lane l holds channels t*16+(l>>4)*4+{0..3}
// of x-row (l&15). f16 pack is in-register; no LDS, no syncthreads.
__global__ __launch_bounds__(256) void gemm_count(const float* __restrict__ x,
                                                  const unsigned short* __restrict__ Wsw,
                                                  const float* __restrict__ att_s,
                                                  const float* __restrict__ att_d,
                                                  const int* __restrict__ dstv,
                                                  unsigned short* __restrict__ hb,
                                                  float* __restrict__ a_src,
                                                  float* __restrict__ a_dst,
                                                  int* __restrict__ counts,
                                                  int* __restrict__ rank) {
  if (blockIdx.x >= GEMM_BLOCKS) {  // ---- count role: one atomic pass, rank recorded ----
    int base = (blockIdx.x - GEMM_BLOCKS) * 512 + threadIdx.x;
#pragma unroll
    for (int k = 0; k < 2; ++k) {
      int e = base + k * 256;
      if (e < N_EDGES) rank[e] = atomicAdd(&counts[dstv[e]], 1);
    }
    return;
  }

  const int wave = threadIdx.x >> 6;
  const int l = threadIdx.x & 63;
  const int q = l >> 4;
  const int m = l & 15;
  const int mrow = blockIdx.x * 64 + wave * 16 + m;
  const bool mvalid = mrow < N_NODES;
  const int rc = mvalid ? mrow : (N_NODES - 1);

  // x fragment (B-operand): lane provides x[row=l&15][k=(l>>4)*8 + kc*32 + j]
  f16x8 a[4];
  const float* xr = x + (size_t)rc * IN_CH + q * 8;
#pragma unroll
  for (int kc = 0; kc < 4; ++kc) {
    float4 u = *(const float4*)(xr + kc * 32);
    float4 v = *(const float4*)(xr + kc * 32 + 4);
    uint32x4 t;
    t[0] = f2h2(u.x, u.y);
    t[1] = f2h2(u.z, u.w);
    t[2] = f2h2(v.x, v.y);
    t[3] = f2h2(v.z, v.w);
    a[kc] = __builtin_bit_cast(f16x8, t);
  }

  float as[4] = {0.f, 0.f, 0.f, 0.f};
  float ad[4] = {0.f, 0.f, 0.f, 0.f};
  unsigned short* hrow = hb + (size_t)mrow * HC;

#pragma unroll
  for (int t = 0; t < 16; ++t) {
    f32x4 acc = {0.f, 0.f, 0.f, 0.f};
#pragma unroll
    for (int kc = 0; kc < 4; ++kc) {
      f16x8 w = *(const f16x8*)(Wsw + ((size_t)(t * 4 + kc) * 64 + l) * 8);
      acc = __builtin_amdgcn_mfma_f32_16x16x32_f16(w, a[kc], acc, 0, 0, 0);
    }
    const int ch = t * 16 + q * 4;      // 4 consecutive channels in this lane
    const int hh = t >> 2;              // head = ch/64 (static under unroll)
    float4 sv = *(const float4*)(att_s + ch);
    float4 dv = *(const float4*)(att_d + ch);
    as[hh] += acc[0] * sv.x + acc[1] * sv.y + acc[2] * sv.z + acc[3] * sv.w;
    ad[hh] += acc[0] * dv.x + acc[1] * dv.y + acc[2] * dv.z + acc[3] * dv.w;
    if (mvalid) {
      uint2 p;
      p.x = f2h2(acc[0], acc[1]);
      p.y = f2h2(acc[2], acc[3]);
      *(uint2*)(hrow + ch) = p;  // 8B aligned (ch multiple of 4)
    }
  }

  // reduce logits across the 4 q-groups (channel slices)
#pragma unroll
  for (int h = 0; h < 4; ++h) {
    as[h] += __shfl_xor(as[h], 16);
    as[h] += __shfl_xor(as[h], 32);
    ad[h] += __shfl_xor(ad[h], 16);
    ad[h] += __shfl_xor(ad[h], 32);
  }
  if (l < 16 && mvalid) {
    *(float4*)(a_src + (size_t)mrow * 4) = make_float4(as[0], as[1], as[2], as[3]);
    *(float4*)(a_dst + (size_t)mrow * 4) = make_float4(ad[0], ad[1], ad[2], ad[3]);
  }
}

// ---------------- scan1: per-block (1024 nodes) exclusive scan + block sums ----------------
// offsets stay PARTIAL (per-scanblock); consumers add the bsums prefix inline.
__global__ __launch_bounds__(256) void scan1(const int* __restrict__ counts,
                                             int* __restrict__ offsets,
                                             int* __restrict__ bsums) {
  __shared__ int sd[256];
  const int base = blockIdx.x * 1024;
  const int t = threadIdx.x;
  int v[4];
  int tsum = 0;
#pragma unroll
  for (int k = 0; k < 4; ++k) {
    int i = base + t * 4 + k;
    v[k] = (i < N_NODES) ? counts[i] : 0;
    tsum += v[k];
  }
  sd[t] = tsum;
  __syncthreads();
  for (int off = 1; off < 256; off <<= 1) {
    int xval = (t >= off) ? sd[t - off] : 0;
    __syncthreads();
    sd[t] += xval;
    __syncthreads();
  }
  int excl = sd[t] - tsum;
  int run = excl;
#pragma unroll
  for (int k = 0; k < 4; ++k) {
    int i = base + t * 4 + k;
    if (i < N_NODES) offsets[i] = run;
    run += v[k];
  }
  if (t == 255) bsums[blockIdx.x] = sd[255];
}

// inline bsums exclusive-prefix: wave-scan 49 values into LDS (per block)
__device__ __forceinline__ void load_prefix(const int* __restrict__ bsums, int* sadd) {
  if (threadIdx.x < 64) {
    int lane = threadIdx.x;
    int b = (lane < SCAN_BLOCKS) ? bsums[lane] : 0;
    int v = b;
#pragma unroll
    for (int o = 1; o < 64; o <<= 1) {
      int t = __shfl_up(v, o);
      if (lane >= o) v += t;
    }
    if (lane < SCAN_BLOCKS) sadd[lane] = v - b;  // exclusive prefix
  }
  __syncthreads();
}

// ---------------- scatter: atomic-free, one 16B record {s, ex01, ex23, 0} per edge ----------------
__global__ __launch_bounds__(256) void scatter_k(const int* __restrict__ src,
                                                 const int* __restrict__ dst,
                                                 const int* __restrict__ rank,
                                                 const int* __restrict__ offsets,
                                                 const int* __restrict__ bsums,
                                                 const float* __restrict__ a_src,
                                                 const float* __restrict__ a_dst,
                                                 uint4* __restrict__ rec) {
  __shared__ int sadd[SCAN_BLOCKS];
  load_prefix(bsums, sadd);
  int e = blockIdx.x * 256 + threadIdx.x;
  if (e < N_EDGES) {
    int s = src[e];
    int d = dst[e];
    float4 as = *(const float4*)(a_src + s * 4);
    float4 ad = *(const float4*)(a_dst + d * 4);
    float ex0 = __expf(lrelu(as.x + ad.x));
    float ex1 = __expf(lrelu(as.y + ad.y));
    float ex2 = __expf(lrelu(as.z + ad.z));
    float ex3 = __expf(lrelu(as.w + ad.w));
    int pos = offsets[d] + sadd[d >> 10] + rank[e];
    rec[pos] = make_uint4((unsigned)s, f2h2(ex0, ex1), f2h2(ex2, ex3), 0u);
  }
}

// ---------------- aggregate: 4 edge groups x 16 lanes, 2 edges in flight per group ----------------
__global__ __launch_bounds__(256) void aggregate(const unsigned short* __restrict__ hb,
                                                 const float* __restrict__ a_src,
                                                 const float* __restrict__ a_dst,
                                                 const int* __restrict__ counts,
                                                 const int* __restrict__ offsets,
                                                 const int* __restrict__ bsums,
                                                 const uint4* __restrict__ rec,
                                                 const float* __restrict__ bias,
                                                 float* __restrict__ out) {
  __shared__ int sadd[SCAN_BLOCKS];
  load_prefix(bsums, sadd);
  const int node = blockIdx.x * 4 + (threadIdx.x >> 6);
  const int l = threadIdx.x & 63;
  const int g = l >> 4;   // edge-parity group 0..3
  const int q = l & 15;   // channel slice: 16 channels at c0=q*16
  const int hd = q >> 2;
  const int cb = q * 32;  // byte offset into 512B row
  const int deg = counts[node];
  const int start = offsets[node] + sadd[node >> 10];
  const char* hbase = (const char*)hb;

  float denom = 0.f;
  float acc[16];
#pragma unroll
  for (int k = 0; k < 16; ++k) acc[k] = 0.f;

  // group g covers edge indices {j+g, j+g+4} for j = 0,8,16,...
  for (int j = 0; j + g < deg; j += 8) {
    int i0 = start + j + g;
    bool v1 = (j + g + 4) < deg;
    int i1 = v1 ? (i0 + 4) : i0;
    // two broadcast 16B record loads
    uint4 r0 = rec[i0];
    uint4 r1 = rec[i1];
    int s0 = (int)r0.x;
    int s1 = (int)r1.x;
    float ex0 = exhalf(r0, hd);
    float ex1 = v1 ? exhalf(r1, hd) : 0.f;
    // two independent 32B h gathers
    const char* hp0 = hbase + (size_t)s0 * 512 + cb;
    const char* hp1 = hbase + (size_t)s1 * 512 + cb;
    uint4 A0 = *(const uint4*)hp0;
    uint4 A1 = *(const uint4*)(hp0 + 16);
    uint4 B0 = *(const uint4*)hp1;
    uint4 B1 = *(const uint4*)(hp1 + 16);
    denom += ex0 + ex1;
    fma2(acc[0],  acc[1],  A0.x, ex0);  fma2(acc[2],  acc[3],  A0.y, ex0);
    fma2(acc[4],  acc[5],  A0.z, ex0);  fma2(acc[6],  acc[7],  A0.w, ex0);
    fma2(acc[8],  acc[9],  A1.x, ex0);  fma2(acc[10], acc[11], A1.y, ex0);
    fma2(acc[12], acc[13], A1.z, ex0);  fma2(acc[14], acc[15], A1.w, ex0);
    fma2(acc[0],  acc[1],  B0.x, ex1);  fma2(acc[2],  acc[3],  B0.y, ex1);
    fma2(acc[4],  acc[5],  B0.z, ex1);  fma2(acc[6],  acc[7],  B0.w, ex1);
    fma2(acc[8],  acc[9],  B1.x, ex1);  fma2(acc[10], acc[11], B1.y, ex1);
    fma2(acc[12], acc[13], B1.z, ex1);  fma2(acc[14], acc[15], B1.w, ex1);
  }

  // combine the 4 edge groups
  denom += __shfl_xor(denom, 16);
  denom += __shfl_xor(denom, 32);
#pragma unroll
  for (int k = 0; k < 16; ++k) {
    acc[k] += __shfl_xor(acc[k], 16);
    acc[k] += __shfl_xor(acc[k], 32);
  }

  // self-loop (identical across groups; added once per lane)
  float es = a_src[node * HEADS + hd] + a_dst[node * HEADS + hd];
  float exs = __expf(lrelu(es));
  denom += exs;
  const char* hp = hbase + (size_t)node * 512 + cb;
  uint4 h0 = *(const uint4*)hp;
  uint4 h1 = *(const uint4*)(hp + 16);
  fma2(acc[0],  acc[1],  h0.x, exs);  fma2(acc[2],  acc[3],  h0.y, exs);
  fma2(acc[4],  acc[5],  h0.z, exs);  fma2(acc[6],  acc[7],  h0.w, exs);
  fma2(acc[8],  acc[9],  h1.x, exs);  fma2(acc[10], acc[11], h1.y, exs);
  fma2(acc[12], acc[13], h1.z, exs);  fma2(acc[14], acc[15], h1.w, exs);

  float inv = 1.f / (denom + 1e-16f);
  // each group stores its own float4 slice: channels q*16 + g*4 .. +3
  int c = q * 16 + g * 4;
  float4 bv = *(const float4*)(bias + c);
  float4 o = make_float4(acc[g * 4 + 0] * inv + bv.x, acc[g * 4 + 1] * inv + bv.y,
                         acc[g * 4 + 2] * inv + bv.z, acc[g * 4 + 3] * inv + bv.w);
  *(float4*)(out + (size_t)node * HC + c) = o;
}

extern "C" void kernel_launch(void* const* d_in, const int* in_sizes, int n_in,
                              void* d_out, int out_size, void* d_ws, size_t ws_size,
                              hipStream_t stream) {
  const float* x     = (const float*)d_in[0];
  const int*   ei    = (const int*)d_in[1];
  const float* W     = (const float*)d_in[2];
  const float* att_s = (const float*)d_in[3];
  const float* att_d = (const float*)d_in[4];
  const float* bias  = (const float*)d_in[5];
  float* out = (float*)d_out;

  char* ws = (char*)d_ws;
  unsigned short* hb  = (unsigned short*)(ws + HB_OFF);
  unsigned short* Wsw = (unsigned short*)(ws + WSW_OFF);
  float* a_src  = (float*)(ws + ASRC_OFF);
  float* a_dst  = (float*)(ws + ADST_OFF);
  int* counts   = (int*)(ws + COUNTS_OFF);
  int* offsets  = (int*)(ws + OFFSETS_OFF);
  int* bsums    = (int*)(ws + BSUMS_OFF);
  int* rank     = (int*)(ws + RANK_OFF);
  uint4* rec    = (uint4*)(ws + REC_OFF);

  const int* src = ei;             // edge_index[0]
  const int* dst = ei + N_EDGES;   // edge_index[1]

  init_k<<<16 + 196, 256, 0, stream>>>(W, Wsw, counts);
  gemm_count<<<GEMM_BLOCKS + COUNT_BLOCKS, 256, 0, stream>>>(
      x, Wsw, att_s, att_d, dst, hb, a_src, a_dst, counts, rank);
  scan1<<<SCAN_BLOCKS, 256, 0, stream>>>(counts, offsets, bsums);
  scatter_k<<<3125, 256, 0, stream>>>(src, dst, rank, offsets, bsums, a_src, a_dst, rec);
  aggregate<<<12500, 256, 0, stream>>>(hb, a_src, a_dst, counts, offsets, bsums, rec, bias, out);
}